// Round 8
// baseline (536.127 us; speedup 1.0000x reference)
//
#include <hip/hip_runtime.h>
#include <cstdint>
#include <cstddef>

// ---------------- types ----------------
typedef __attribute__((ext_vector_type(8))) _Float16 half8;   // MFMA f16 A/B frag (4 VGPRs)
typedef __attribute__((ext_vector_type(4))) _Float16 half4;
typedef __attribute__((ext_vector_type(4))) float    floatx4; // MFMA C/D frag

static constexpr int B_ROWS = 16384;
static constexpr int IN_DIM = 256;
static constexpr int H_DIM  = 512;
static constexpr int NB     = 16;

__device__ __forceinline__ float fast_tanh(float x) {
  float ax = fabsf(x);
  float e  = __expf(2.0f * ax);             // e >= 1, inf-safe
  float t  = 1.0f - 2.0f / (e + 1.0f);
  return copysignf(t, x);
}

// ---------------- prep: x column-stats partials (blocks 0..127) + coeff cvt+transpose ----
// cvt folds K_n = exp(-2 c_n^2) into fp16 coeffs AND writes K-blocked layout:
//   Bt[kstep][o][ksub]  (kstep = k/32, ksub = k%32, k = i*16+n)
// so a wave's B-frag load per K-step is 1 KB contiguous (global->VGPR, L2-resident).
__global__ __launch_bounds__(256) void prep_k(const float* __restrict__ c1, _Float16* __restrict__ d1,
                                              const float* __restrict__ c2, _Float16* __restrict__ d2,
                                              const float* __restrict__ X,
                                              float* __restrict__ ps, float* __restrict__ ps2) {
  const int bx = blockIdx.x;
  if (bx < 128) {
    // ---- stats on X: cols=256 (4 col-groups of 64), 32 row-segs of 512 ----
    int c     = (bx & 3) * 64 + (threadIdx.x & 63);
    int chunk = threadIdx.x >> 6;
    int seg   = bx >> 2;
    int r0    = seg * 512;
    double s = 0.0, s2 = 0.0;
    for (int r = r0 + chunk; r < r0 + 512; r += 4) {
      float v = X[(size_t)r * IN_DIM + c];
      s += v; s2 += (double)v * (double)v;
    }
    __shared__ float Ls[256], Ls2[256];
    Ls[threadIdx.x] = (float)s; Ls2[threadIdx.x] = (float)s2;
    __syncthreads();
    if (chunk == 0) {
      int cl = threadIdx.x;
      ps [(size_t)seg * IN_DIM + c] = Ls[cl]  + Ls[cl + 64]  + Ls[cl + 128]  + Ls[cl + 192];
      ps2[(size_t)seg * IN_DIM + c] = Ls2[cl] + Ls2[cl + 64] + Ls2[cl + 128] + Ls2[cl + 192];
    }
  } else {
    // ---- coeff conversion + transpose, grid-stride (float4 granularity) ----
    const size_t n41 = (size_t)H_DIM * IN_DIM * NB / 4;
    const size_t n42 = (size_t)H_DIM * H_DIM * NB / 4;
    size_t tot = n41 + n42;
    int nb_blocks = gridDim.x - 128;
    for (size_t idx = (size_t)(bx - 128) * 256 + threadIdx.x; idx < tot;
         idx += (size_t)nb_blocks * 256) {
      const float4* sp; _Float16* dp; size_t j; int C;
      if (idx < n41) { sp = (const float4*)c1; dp = d1; j = idx;       C = IN_DIM; }
      else           { sp = (const float4*)c2; dp = d2; j = idx - n41; C = H_DIM;  }
      float4 v = sp[j];
      int perO = C * 4;                       // float4s per output row
      int o    = (int)(j / perO);
      int rem  = (int)(j - (size_t)o * perO);
      int i    = rem >> 2;
      int n0   = (rem & 3) * 4;               // n-index of element 0
      int kblk = i >> 1;
      int ksub = (i & 1) * 16 + n0;
      half4 r;
      float e0 = -2.f + (float)(n0 + 0) * (4.f / 15.f);
      float e1 = -2.f + (float)(n0 + 1) * (4.f / 15.f);
      float e2 = -2.f + (float)(n0 + 2) * (4.f / 15.f);
      float e3 = -2.f + (float)(n0 + 3) * (4.f / 15.f);
      r[0] = (_Float16)(v.x * __expf(-2.f * e0 * e0));
      r[1] = (_Float16)(v.y * __expf(-2.f * e1 * e1));
      r[2] = (_Float16)(v.z * __expf(-2.f * e2 * e2));
      r[3] = (_Float16)(v.w * __expf(-2.f * e3 * e3));
      *(half4*)(dp + ((size_t)kblk * H_DIM + o) * 32 + ksub) = r;
    }
  }
}

// ---------------- stats finalize (float partials) ----------------
__global__ void stats_final_k(const float* __restrict__ ps,
                              const float* __restrict__ ps2,
                              int segs, int cols, int rows,
                              float* __restrict__ mu, float* __restrict__ isd) {
  int c = blockIdx.x * blockDim.x + threadIdx.x;
  if (c >= cols) return;
  double s = 0.0, s2 = 0.0;
  for (int g = 0; g < segs; g++) { s += ps[(size_t)g * cols + c]; s2 += ps2[(size_t)g * cols + c]; }
  double mean = s / rows;
  double var  = (s2 - s * s / rows) / (rows - 1);   // ddof=1
  if (var < 0.0) var = 0.0;
  float sd = (float)sqrt(var);
  mu[c]  = (float)mean;
  isd[c] = 1.0f / (sd + 1e-6f);
}

// ---------------- fused normalize+expand+GEMM+tanh + column-stats partials ----------------
// R7 model (verified vs R6/R7 walls within 5%): per-CU LDS pipe was the wall (~530cyc/block-step
// vs 310 matrix). This round: B never touches LDS — each wave loads its 4 B-frags per K-step
// directly global->VGPR from the K-blocked Bt layout (1KB contiguous per frag, L2-resident).
// VGPR-dest loads mean __syncthreads no longer drains vmcnt: the B pipeline floats across
// barriers with 1-step prefetch. LDS left: A expansion writes (8KB) + A frag reads (16xb128)
// ~= 240 cyc/block-step < matrix 310. 128x128 tile, 4 waves 2x2, grid (128,4)=512 = 2 blocks/CU.
__global__ __launch_bounds__(256, 2) void kan_gemm_fused(const float* __restrict__ X,   // [B, C]
                                                         const float* __restrict__ mu,
                                                         const float* __restrict__ isd,
                                                         const _Float16* __restrict__ Bt, // [K/32][512][32]
                                                         float* __restrict__ Hout,        // [B, 512]
                                                         float* __restrict__ psum,        // [128, 512]
                                                         float* __restrict__ psum2,       // [128, 512]
                                                         int C) {
  const int steps = C >> 1;                 // K = C*16, BK = 32 -> C/2 steps
  __shared__ __align__(16) _Float16 As[2][128 * 32];   // 16 KB; chunk = kseg*128 + row
  __shared__ float Rs1[2][128], Rs2[2][128];           //  2 KB epilogue reduction
  const int tid  = threadIdx.x;
  const int w = tid >> 6, lane = tid & 63;
  const int wm = w & 1, wn = w >> 1;        // 2x2 wave grid
  const int lrow = lane & 15, quad = lane >> 4;
  const int row0 = blockIdx.x * 128;
  const int col0 = blockIdx.y * 128;

  // ---- B direct-global: per-lane base; frag (k,t) at + k*512*32 + t*16*32 elements
  const _Float16* bp = Bt + ((size_t)(col0 + wn * 64 + lrow)) * 32 + quad * 8;

  // ---- A expansion: thread -> row = tid>>1, feature-half eh = tid&1; writes ksegs 2eh, 2eh+1.
  const int erow = tid >> 1, eh = tid & 1;
  const float* xp = X + (size_t)(row0 + erow) * C + eh;   // xn(step k) = xp[2k]

  floatx4 acc[4][4] = {};

  auto expand_store = [&](float v, int ci, int bufi) {
    float xn = fminf(fmaxf((v - mu[ci]) * isd[ci], -3.f), 3.f);
    float Wv = __expf(-2.f * xn * xn - 8.f * xn);
    float g  = __expf((16.f / 15.f) * xn);
    half8 h0, h1;
    float p = Wv;
#pragma unroll
    for (int n = 0; n < 8; n++) { h0[n] = (_Float16)p; p *= g; }
#pragma unroll
    for (int n = 0; n < 8; n++) { h1[n] = (_Float16)p; p *= g; }
    *(half8*)&As[bufi][(size_t)((2 * eh)     * 128 + erow) * 8] = h0;
    *(half8*)&As[bufi][(size_t)((2 * eh + 1) * 128 + erow) * 8] = h1;
  };

  half8 bA[4], bB[4];
  float xv;

  // ---- prologue ----
#pragma unroll
  for (int t = 0; t < 4; t++) bA[t] = *(const half8*)(bp + (size_t)t * 512);
  expand_store(xp[0], eh, 0);
  xv = xp[2];
  __syncthreads();

  // one K-step: prefetch B(k+1)->nxt, expand A(k+1)->As[buf^1], MFMA on As[buf] x cur
  auto body = [&](int k, half8* cur, half8* nxt, int buf) {
    if (k + 1 < steps) {
#pragma unroll
      for (int t = 0; t < 4; t++)
        nxt[t] = *(const half8*)(bp + (size_t)(k + 1) * 16384 + (size_t)t * 512);
      expand_store(xv, 2 * (k + 1) + eh, buf ^ 1);
      if (k + 2 < steps) xv = xp[2 * (k + 2)];
    }
    half8 af[4];
#pragma unroll
    for (int t = 0; t < 4; t++)
      af[t] = *(const half8*)&As[buf][(quad * 128 + wm * 64 + t * 16 + lrow) * 8];
#pragma unroll
    for (int tm = 0; tm < 4; tm++)
#pragma unroll
      for (int tn = 0; tn < 4; tn++)
        acc[tm][tn] = __builtin_amdgcn_mfma_f32_16x16x32_f16(af[tm], cur[tn], acc[tm][tn], 0, 0, 0);
    __syncthreads();
  };

  for (int k = 0; k < steps; k += 2) {      // steps is even (128 or 256)
    body(k,     bA, bB, 0);
    body(k + 1, bB, bA, 1);
  }

  // ---- epilogue: C/D layout col=lane&15, row=quad*4+reg; fused tanh + column partial sums ----
  float s1[4] = {0.f, 0.f, 0.f, 0.f}, s2v[4] = {0.f, 0.f, 0.f, 0.f};
#pragma unroll
  for (int tm = 0; tm < 4; tm++) {
#pragma unroll
    for (int tn = 0; tn < 4; tn++) {
      int gcol = col0 + wn * 64 + tn * 16 + lrow;
#pragma unroll
      for (int r = 0; r < 4; r++) {
        int grow = row0 + wm * 64 + tm * 16 + quad * 4 + r;
        float v = fast_tanh(acc[tm][tn][r]);
        Hout[(size_t)grow * H_DIM + gcol] = v;
        s1[tn] += v; s2v[tn] += v * v;
      }
    }
  }
#pragma unroll
  for (int tn = 0; tn < 4; tn++) {
    s1[tn]  += __shfl_xor(s1[tn], 16);  s1[tn]  += __shfl_xor(s1[tn], 32);
    s2v[tn] += __shfl_xor(s2v[tn], 16); s2v[tn] += __shfl_xor(s2v[tn], 32);
  }
  if (quad == 0) {
#pragma unroll
    for (int tn = 0; tn < 4; tn++) {
      Rs1[wm][wn * 64 + tn * 16 + lrow] = s1[tn];
      Rs2[wm][wn * 64 + tn * 16 + lrow] = s2v[tn];
    }
  }
  __syncthreads();
  if (tid < 128) {
    psum [(size_t)blockIdx.x * H_DIM + col0 + tid] = Rs1[0][tid] + Rs1[1][tid];
    psum2[(size_t)blockIdx.x * H_DIM + col0 + tid] = Rs2[0][tid] + Rs2[1][tid];
  }
}

// ---------------- layer 3 (out dim 1) + skip, fp32, normalize fused ----------------
__global__ __launch_bounds__(256) void layer3_k(const float* __restrict__ H2,
                                                const float* __restrict__ mu,
                                                const float* __restrict__ isd,
                                                const float* __restrict__ C3,
                                                const float* __restrict__ X,
                                                const float* __restrict__ SW,
                                                const float* __restrict__ SB,
                                                float* __restrict__ OUT) {
  int w = threadIdx.x >> 6, lane = threadIdx.x & 63;
  float Kn[NB];
#pragma unroll
  for (int n = 0; n < NB; n++) {
    float c = -2.f + (float)n * (4.f / 15.f);
    Kn[n] = __expf(-2.f * c * c);
  }
  float sb0 = SB[0];
  int row_base = blockIdx.x * 16 + w * 4;
  for (int r = 0; r < 4; r++) {
    int row = row_base + r;
    float s = 0.f;
#pragma unroll
    for (int j = 0; j < 8; j++) {
      int i = lane + 64 * j;
      float hv = H2[(size_t)row * H_DIM + i];
      float xn = fminf(fmaxf((hv - mu[i]) * isd[i], -3.f), 3.f);
      float Wf = __expf(-2.f * xn * xn - 8.f * xn);
      float gf = __expf((16.f / 15.f) * xn);
      const floatx4* cp = (const floatx4*)(C3 + (size_t)i * NB);
      floatx4 c0 = cp[0], c1 = cp[1], c2 = cp[2], c3 = cp[3];
      float p = Wf;
#pragma unroll
      for (int n = 0; n < 4; n++) { s += p * Kn[n]      * c0[n]; p *= gf; }
#pragma unroll
      for (int n = 0; n < 4; n++) { s += p * Kn[n + 4]  * c1[n]; p *= gf; }
#pragma unroll
      for (int n = 0; n < 4; n++) { s += p * Kn[n + 8]  * c2[n]; p *= gf; }
#pragma unroll
      for (int n = 0; n < 4; n++) { s += p * Kn[n + 12] * c3[n]; p *= gf; }
    }
#pragma unroll
    for (int j = 0; j < 4; j++) {
      int i = lane + 64 * j;
      s += X[(size_t)row * IN_DIM + i] * SW[i];
    }
#pragma unroll
    for (int off = 32; off > 0; off >>= 1) s += __shfl_down(s, off);
    if (lane == 0) OUT[row] = s + sb0;
  }
}

// ---------------- launcher ----------------
extern "C" void kernel_launch(void* const* d_in, const int* in_sizes, int n_in,
                              void* d_out, int out_size, void* d_ws, size_t ws_size,
                              hipStream_t stream) {
  const float* x  = (const float*)d_in[0];   // [16384, 256]
  const float* c1 = (const float*)d_in[1];   // [512, 256, 16]
  const float* c2 = (const float*)d_in[2];   // [512, 512, 16]
  const float* c3 = (const float*)d_in[3];   // [1, 512, 16]
  const float* sw = (const float*)d_in[4];   // [1, 256]
  const float* sb = (const float*)d_in[5];   // [1]
  float* out = (float*)d_out;

  const int B = B_ROWS, IN = IN_DIM, H = H_DIM;

  char* ws = (char*)d_ws;
  size_t off = 0;
  auto alloc = [&](size_t bytes) -> void* {
    void* p = ws + off;
    off += (bytes + 255) & ~(size_t)255;
    return p;
  };
  _Float16* Bt1 = (_Float16*)alloc((size_t)H * IN * NB * 2);  //  4 MB  [128][512][32]
  _Float16* Bt2 = (_Float16*)alloc((size_t)H * H  * NB * 2);  //  8 MB  [256][512][32]
  float* H1 = (float*)alloc((size_t)B * H * 4);               // 32 MB
  float* H2 = (float*)alloc((size_t)B * H * 4);               // 32 MB
  float* ps  = (float*)alloc(128 * 512 * 4);                  // 256 KB
  float* ps2 = (float*)alloc(128 * 512 * 4);
  float* mu  = (float*)alloc(512 * 4);
  float* isd = (float*)alloc(512 * 4);

  // ---- prep: x-stats partials + coeff cvt/transpose in one dispatch ----
  prep_k<<<128 + 1024, 256, 0, stream>>>(c1, Bt1, c2, Bt2, x, ps, ps2);
  stats_final_k<<<1, 256, 0, stream>>>(ps, ps2, 32, IN, B, mu, isd);

  // ---- layer 1 (C=256, K=4096); epilogue emits H1 column partials ----
  kan_gemm_fused<<<dim3(B / 128, 4), 256, 0, stream>>>(x, mu, isd, Bt1, H1, ps, ps2, IN);
  stats_final_k<<<2, 256, 0, stream>>>(ps, ps2, 128, H, B, mu, isd);

  // ---- layer 2 (C=512, K=8192); epilogue emits H2 column partials ----
  kan_gemm_fused<<<dim3(B / 128, 4), 256, 0, stream>>>(H1, mu, isd, Bt2, H2, ps, ps2, H);
  stats_final_k<<<2, 256, 0, stream>>>(ps, ps2, 128, H, B, mu, isd);

  // ---- layer 3 + skip (normalize fused) ----
  layer3_k<<<B / 16, 256, 0, stream>>>(H2, mu, isd, c3, x, sw, sb, out);
}